// Round 1
// baseline (1148.603 us; speedup 1.0000x reference)
//
#include <hip/hip_runtime.h>

#define NB 8
#define CIN 3
#define N0 327680
#define N1 81920
#define N2 20480
#define KC 10
#define KA 4

// workspace layout in floats
#define H2_OFF 0ull
#define H2_SZ  ((size_t)NB * 16 * N1)          // 10,485,760 floats
#define H3_OFF (H2_OFF + H2_SZ)
#define H3_SZ  ((size_t)NB * 32 * N2)          // 5,242,880 floats
#define W1T_OFF (H3_OFF + H3_SZ)               // 30*16 = 480
#define W2T_OFF (W1T_OFF + 480)                // 160*32 = 5120
#define W3T_OFF (W2T_OFF + 5120)               // 320*10 = 3200

// ---- tiny prep kernel: transpose weights to [i][o], init out with bias ----
__global__ __launch_bounds__(256) void ktrans(
    const float* __restrict__ w1, const float* __restrict__ w2,
    const float* __restrict__ w3, const float* __restrict__ b3,
    float* __restrict__ ws, float* __restrict__ out) {
  int t = blockIdx.x * 256 + threadIdx.x;
  if (t < 480)  ws[W1T_OFF + (size_t)(t % 30)  * 16 + (t / 30)]  = w1[t];
  if (t < 5120) ws[W2T_OFF + (size_t)(t % 160) * 32 + (t / 160)] = w2[t];
  if (t < 3200) ws[W3T_OFF + (size_t)(t % 320) * 10 + (t / 320)] = w3[t];
  if (t < 80)   out[t] = b3[t % 10];
}

// ---- conv1 (3->16, K=10) fused with maxpool0 ----
__global__ __launch_bounds__(256) void k1(
    const float* __restrict__ x, const int* __restrict__ conv_t0,
    const int* __restrict__ adj0, const int* __restrict__ pool0,
    const float* __restrict__ wt, const float* __restrict__ b1,
    float* __restrict__ h2) {
  int t = blockIdx.x * 256 + threadIdx.x;
  int b = t / N1, j = t % N1;
  int pj = pool0[j];
  int idxs[KA][KC];
#pragma unroll
  for (int p = 0; p < KA; ++p) {
    int pos = adj0[pj * KA + p];
#pragma unroll
    for (int k = 0; k < KC; ++k) idxs[p][k] = conv_t0[pos * KC + k];
  }
  const float* xb = x + (size_t)b * CIN * N0;
  float acc[KA][16];
#pragma unroll
  for (int p = 0; p < KA; ++p)
#pragma unroll
    for (int o = 0; o < 16; ++o) acc[p][o] = 0.f;

  for (int c = 0; c < CIN; ++c) {
    const float* xc = xb + (size_t)c * N0;
#pragma unroll
    for (int k = 0; k < KC; ++k) {
      int i = c * KC + k;
      float v0 = xc[idxs[0][k]];
      float v1 = xc[idxs[1][k]];
      float v2 = xc[idxs[2][k]];
      float v3 = xc[idxs[3][k]];
#pragma unroll
      for (int o = 0; o < 16; ++o) {
        float w = wt[i * 16 + o];   // uniform -> s_load
        acc[0][o] += v0 * w;
        acc[1][o] += v1 * w;
        acc[2][o] += v2 * w;
        acc[3][o] += v3 * w;
      }
    }
  }
#pragma unroll
  for (int o = 0; o < 16; ++o) {
    float m = fmaxf(fmaxf(acc[0][o], acc[1][o]), fmaxf(acc[2][o], acc[3][o])) + b1[o];
    h2[((size_t)b * 16 + o) * N1 + j] = m;
  }
}

// ---- conv2 (16->32, K=10) fused with maxpool1 ----
__global__ __launch_bounds__(256, 1) void k2(
    const float* __restrict__ h2, const int* __restrict__ conv_t1,
    const int* __restrict__ adj1, const int* __restrict__ pool1,
    const float* __restrict__ wt, const float* __restrict__ b2,
    float* __restrict__ h3) {
  int t = blockIdx.x * 256 + threadIdx.x;
  int b = t / N2, j = t % N2;
  int pj = pool1[j];
  int idxs[KA][KC];
#pragma unroll
  for (int p = 0; p < KA; ++p) {
    int pos = adj1[pj * KA + p];
#pragma unroll
    for (int k = 0; k < KC; ++k) idxs[p][k] = conv_t1[pos * KC + k];
  }
  const float* hb = h2 + (size_t)b * 16 * N1;
  float acc[KA][32];
#pragma unroll
  for (int p = 0; p < KA; ++p)
#pragma unroll
    for (int o = 0; o < 32; ++o) acc[p][o] = 0.f;

  for (int c = 0; c < 16; ++c) {
    const float* hc = hb + (size_t)c * N1;
#pragma unroll
    for (int k = 0; k < KC; ++k) {
      int i = c * KC + k;
      float v0 = hc[idxs[0][k]];
      float v1 = hc[idxs[1][k]];
      float v2 = hc[idxs[2][k]];
      float v3 = hc[idxs[3][k]];
#pragma unroll
      for (int o = 0; o < 32; ++o) {
        float w = wt[i * 32 + o];   // uniform -> s_load
        acc[0][o] += v0 * w;
        acc[1][o] += v1 * w;
        acc[2][o] += v2 * w;
        acc[3][o] += v3 * w;
      }
    }
  }
#pragma unroll
  for (int o = 0; o < 32; ++o) {
    float m = fmaxf(fmaxf(acc[0][o], acc[1][o]), fmaxf(acc[2][o], acc[3][o])) + b2[o];
    h3[((size_t)b * 32 + o) * N2 + j] = m;
  }
}

// ---- conv3 (32->10, K=10) fused with mean-reduce ----
__global__ __launch_bounds__(256) void k3(
    const float* __restrict__ h3, const int* __restrict__ conv_t2,
    const float* __restrict__ wt, float* __restrict__ out) {
  int t = blockIdx.x * 256 + threadIdx.x;
  int b = t / N2, j = t % N2;
  int idxs[KC];
#pragma unroll
  for (int k = 0; k < KC; ++k) idxs[k] = conv_t2[j * KC + k];
  const float* hb = h3 + (size_t)b * 32 * N2;
  float acc[10];
#pragma unroll
  for (int o = 0; o < 10; ++o) acc[o] = 0.f;

  for (int c = 0; c < 32; ++c) {
    const float* hc = hb + (size_t)c * N2;
#pragma unroll
    for (int k = 0; k < KC; ++k) {
      int i = c * KC + k;
      float v = hc[idxs[k]];
#pragma unroll
      for (int o = 0; o < 10; ++o) acc[o] += v * wt[i * 10 + o];  // uniform -> s_load
    }
  }
  // wave-level reduce (all lanes in a wave share b), then one atomic per wave
#pragma unroll
  for (int o = 0; o < 10; ++o) {
    float v = acc[o];
    for (int off = 32; off > 0; off >>= 1) v += __shfl_down(v, off);
    if ((threadIdx.x & 63) == 0) atomicAdd(&out[b * 10 + o], v * (1.0f / N2));
  }
}

extern "C" void kernel_launch(void* const* d_in, const int* in_sizes, int n_in,
                              void* d_out, int out_size, void* d_ws, size_t ws_size,
                              hipStream_t stream) {
  const float* x       = (const float*)d_in[0];
  const int*   conv_t0 = (const int*)d_in[1];
  const int*   conv_t1 = (const int*)d_in[2];
  const int*   conv_t2 = (const int*)d_in[3];
  const int*   adj0    = (const int*)d_in[4];
  const int*   adj1    = (const int*)d_in[5];
  const int*   pool0   = (const int*)d_in[6];
  const int*   pool1   = (const int*)d_in[7];
  const float* w1      = (const float*)d_in[8];
  const float* b1      = (const float*)d_in[9];
  const float* w2      = (const float*)d_in[10];
  const float* b2      = (const float*)d_in[11];
  const float* w3      = (const float*)d_in[12];
  const float* b3      = (const float*)d_in[13];
  float* out = (float*)d_out;
  float* ws  = (float*)d_ws;

  ktrans<<<20, 256, 0, stream>>>(w1, w2, w3, b3, ws, out);
  k1<<<(NB * N1) / 256, 256, 0, stream>>>(x, conv_t0, adj0, pool0,
                                          ws + W1T_OFF, b1, ws + H2_OFF);
  k2<<<(NB * N2) / 256, 256, 0, stream>>>(ws + H2_OFF, conv_t1, adj1, pool1,
                                          ws + W2T_OFF, b2, ws + H3_OFF);
  k3<<<(NB * N2) / 256, 256, 0, stream>>>(ws + H3_OFF, conv_t2,
                                          ws + W3T_OFF, out);
}

// Round 2
// 1051.306 us; speedup vs baseline: 1.0925x; 1.0925x over previous
//
#include <hip/hip_runtime.h>

#define NB 8
#define CIN 3
#define N0 327680
#define N1 81920
#define N2 20480
#define KC 10
#define KA 4

// ---- workspace layout (units: 4-byte words) ----
// xT [8][N0][3] floats; later ALIASED by h3 [8][N2][32] (xT dead after k1)
#define XT_OFF    0ull
#define H3_OFF    0ull
#define H2_OFF    7864320ull                 // h2 [8][N1][16] = 10,485,760
#define FIDX0_OFF 18350080ull                // int [N1][40]   = 3,276,800
#define FIDX1_OFF 21626880ull                // int [N2][40]   =   819,200
#define W1_OFF    22446080ull                // [k][c][o] 10*3*16  = 480
#define W2_OFF    22446560ull                // [k][c][o] 10*16*32 = 5120
#define W3_OFF    22451680ull                // [k][c][o] 10*32*10 = 3200
// total = 22,454,880 words = 89.8 MB

// ---- weights -> [k][c][o] layout, init out with bias3 ----
__global__ __launch_bounds__(256) void kprep(
    const float* __restrict__ w1, const float* __restrict__ w2,
    const float* __restrict__ w3, const float* __restrict__ b3,
    float* __restrict__ ws, float* __restrict__ out) {
  int t = blockIdx.x * 256 + threadIdx.x;
  if (t < 480)  { int o = t % 16, r = t / 16, c = r % 3,  k = r / 3;
                  ws[W1_OFF + t] = w1[(o * 3  + c) * KC + k]; }
  if (t < 5120) { int o = t % 32, r = t / 32, c = r % 16, k = r / 16;
                  ws[W2_OFF + t] = w2[(o * 16 + c) * KC + k]; }
  if (t < 3200) { int o = t % 10, r = t / 10, c = r % 32, k = r / 32;
                  ws[W3_OFF + t] = w3[(o * 32 + c) * KC + k]; }
  if (t < 80)   out[t] = b3[t % 10];
}

// ---- x [b][c][n] -> xT [b][n][3] ----
__global__ __launch_bounds__(256) void ktransx(
    const float* __restrict__ x, float* __restrict__ xT) {
  int blk = blockIdx.x;
  int b = blk / (N0 / 256);
  int n = (blk % (N0 / 256)) * 256 + threadIdx.x;
  size_t src = (size_t)b * CIN * N0 + n;
  size_t dst = ((size_t)b * N0 + n) * 3;
  xT[dst + 0] = x[src];
  xT[dst + 1] = x[src + N0];
  xT[dst + 2] = x[src + 2 * (size_t)N0];
}

// ---- fused index tables, pre-scaled by element stride ----
__global__ __launch_bounds__(256) void kfidx(
    const int* __restrict__ conv_t0, const int* __restrict__ conv_t1,
    const int* __restrict__ adj0, const int* __restrict__ adj1,
    const int* __restrict__ pool0, const int* __restrict__ pool1,
    int* __restrict__ fidx0, int* __restrict__ fidx1) {
  int j = blockIdx.x * 256 + threadIdx.x;
  int pj = pool0[j];
#pragma unroll
  for (int p = 0; p < KA; ++p) {
    int pos = adj0[pj * KA + p];
#pragma unroll
    for (int k = 0; k < KC; ++k)
      fidx0[(size_t)j * 40 + p * KC + k] = conv_t0[pos * KC + k] * 3;   // xT stride 3
  }
  if (j < N2) {
    int qj = pool1[j];
#pragma unroll
    for (int p = 0; p < KA; ++p) {
      int pos = adj1[qj * KA + p];
#pragma unroll
      for (int k = 0; k < KC; ++k)
        fidx1[(size_t)j * 40 + p * KC + k] = conv_t1[pos * KC + k] * 16; // h2 stride 16
    }
  }
}

// ---- conv1 (3->16) + maxpool0 : xT gathers are 12B, L2-resident per XCD ----
__global__ __launch_bounds__(256) void k1(
    const float* __restrict__ xT, const int* __restrict__ fidx0,
    const float* __restrict__ wt, const float* __restrict__ b1,
    float* __restrict__ h2) {
  int blk = blockIdx.x;
  int b = blk & 7;                      // XCD-pinned batch
  int j = (blk >> 3) * 256 + threadIdx.x;
  const int* fi = fidx0 + (size_t)j * 40;
  int idx[40];
#pragma unroll
  for (int q = 0; q < 10; ++q) {
    int4 v = ((const int4*)fi)[q];
    idx[q * 4 + 0] = v.x; idx[q * 4 + 1] = v.y;
    idx[q * 4 + 2] = v.z; idx[q * 4 + 3] = v.w;
  }
  const float* xb = xT + (size_t)b * N0 * 3;
  float m[16];
#pragma unroll
  for (int o = 0; o < 16; ++o) m[o] = -1e30f;

#pragma unroll
  for (int p = 0; p < KA; ++p) {
    float acc[16];
#pragma unroll
    for (int o = 0; o < 16; ++o) acc[o] = 0.f;
#pragma unroll
    for (int k = 0; k < KC; ++k) {
      const float* px = xb + idx[p * KC + k];
      float v0 = px[0], v1 = px[1], v2 = px[2];
      const float* w0 = wt + (k * 3 + 0) * 16;
      const float* w1r = wt + (k * 3 + 1) * 16;
      const float* w2r = wt + (k * 3 + 2) * 16;
#pragma unroll
      for (int o = 0; o < 16; ++o)
        acc[o] = fmaf(v0, w0[o], fmaf(v1, w1r[o], fmaf(v2, w2r[o], acc[o])));
    }
#pragma unroll
    for (int o = 0; o < 16; ++o) m[o] = fmaxf(m[o], acc[o]);
  }
  float* dst = h2 + ((size_t)b * N1 + j) * 16;
#pragma unroll
  for (int o = 0; o < 16; ++o) dst[o] = m[o] + b1[o];
}

// ---- conv2 (16->32) + maxpool1 : h2 gathers are one 64B line ----
__global__ __launch_bounds__(256) void k2(
    const float* __restrict__ h2, const int* __restrict__ fidx1,
    const float* __restrict__ wt, const float* __restrict__ b2,
    float* __restrict__ h3) {
  int blk = blockIdx.x;
  int b = blk & 7;
  int j = (blk >> 3) * 256 + threadIdx.x;
  const int* fi = fidx1 + (size_t)j * 40;
  int idx[40];
#pragma unroll
  for (int q = 0; q < 10; ++q) {
    int4 v = ((const int4*)fi)[q];
    idx[q * 4 + 0] = v.x; idx[q * 4 + 1] = v.y;
    idx[q * 4 + 2] = v.z; idx[q * 4 + 3] = v.w;
  }
  const float* hb = h2 + (size_t)b * N1 * 16;
  float m[32];
#pragma unroll
  for (int o = 0; o < 32; ++o) m[o] = -1e30f;

#pragma unroll
  for (int p = 0; p < KA; ++p) {
    float acc[32];
#pragma unroll
    for (int o = 0; o < 32; ++o) acc[o] = 0.f;
#pragma unroll
    for (int k = 0; k < KC; ++k) {
      const float4* ph = (const float4*)(hb + idx[p * KC + k]);
      float4 va = ph[0], vb = ph[1], vc = ph[2], vd = ph[3];
      float v[16] = {va.x, va.y, va.z, va.w, vb.x, vb.y, vb.z, vb.w,
                     vc.x, vc.y, vc.z, vc.w, vd.x, vd.y, vd.z, vd.w};
      const float* wk = wt + k * 16 * 32;
#pragma unroll
      for (int c = 0; c < 16; ++c)
#pragma unroll
        for (int o = 0; o < 32; ++o)
          acc[o] = fmaf(v[c], wk[c * 32 + o], acc[o]);
    }
#pragma unroll
    for (int o = 0; o < 32; ++o) m[o] = fmaxf(m[o], acc[o]);
  }
  float* dst = h3 + ((size_t)b * N2 + j) * 32;
#pragma unroll
  for (int o = 0; o < 32; ++o) dst[o] = m[o] + b2[o];
}

// ---- conv3 (32->10) + mean ----
__global__ __launch_bounds__(256) void k3(
    const float* __restrict__ h3, const int* __restrict__ conv_t2,
    const float* __restrict__ wt, float* __restrict__ out) {
  int blk = blockIdx.x;
  int b = blk & 7;
  int j = (blk >> 3) * 256 + threadIdx.x;
  int idx[KC];
#pragma unroll
  for (int k = 0; k < KC; ++k) idx[k] = conv_t2[(size_t)j * KC + k] * 32;
  const float* hb = h3 + (size_t)b * N2 * 32;
  float acc[10];
#pragma unroll
  for (int o = 0; o < 10; ++o) acc[o] = 0.f;

#pragma unroll
  for (int k = 0; k < KC; ++k) {
    const float4* ph = (const float4*)(hb + idx[k]);
    float v[32];
#pragma unroll
    for (int q = 0; q < 8; ++q) {
      float4 t = ph[q];
      v[q * 4 + 0] = t.x; v[q * 4 + 1] = t.y; v[q * 4 + 2] = t.z; v[q * 4 + 3] = t.w;
    }
    const float* wk = wt + k * 32 * 10;
#pragma unroll
    for (int c = 0; c < 32; ++c)
#pragma unroll
      for (int o = 0; o < 10; ++o)
        acc[o] = fmaf(v[c], wk[c * 10 + o], acc[o]);
  }
#pragma unroll
  for (int o = 0; o < 10; ++o) {
    float v = acc[o];
    for (int off = 32; off > 0; off >>= 1) v += __shfl_down(v, off);
    if ((threadIdx.x & 63) == 0) atomicAdd(&out[b * 10 + o], v * (1.0f / N2));
  }
}

extern "C" void kernel_launch(void* const* d_in, const int* in_sizes, int n_in,
                              void* d_out, int out_size, void* d_ws, size_t ws_size,
                              hipStream_t stream) {
  const float* x       = (const float*)d_in[0];
  const int*   conv_t0 = (const int*)d_in[1];
  const int*   conv_t1 = (const int*)d_in[2];
  const int*   conv_t2 = (const int*)d_in[3];
  const int*   adj0    = (const int*)d_in[4];
  const int*   adj1    = (const int*)d_in[5];
  const int*   pool0   = (const int*)d_in[6];
  const int*   pool1   = (const int*)d_in[7];
  const float* w1      = (const float*)d_in[8];
  const float* b1      = (const float*)d_in[9];
  const float* w2      = (const float*)d_in[10];
  const float* b2      = (const float*)d_in[11];
  const float* w3      = (const float*)d_in[12];
  const float* b3      = (const float*)d_in[13];
  float* out = (float*)d_out;
  float* ws  = (float*)d_ws;

  kprep<<<20, 256, 0, stream>>>(w1, w2, w3, b3, ws, out);
  ktransx<<<NB * (N0 / 256), 256, 0, stream>>>(x, ws + XT_OFF);
  kfidx<<<N1 / 256, 256, 0, stream>>>(conv_t0, conv_t1, adj0, adj1, pool0, pool1,
                                      (int*)(ws + FIDX0_OFF), (int*)(ws + FIDX1_OFF));
  k1<<<NB * (N1 / 256), 256, 0, stream>>>(ws + XT_OFF, (const int*)(ws + FIDX0_OFF),
                                          ws + W1_OFF, b1, ws + H2_OFF);
  k2<<<NB * (N2 / 256), 256, 0, stream>>>(ws + H2_OFF, (const int*)(ws + FIDX1_OFF),
                                          ws + W2_OFF, b2, ws + H3_OFF);
  k3<<<NB * (N2 / 256), 256, 0, stream>>>(ws + H3_OFF, conv_t2, ws + W3_OFF, out);
}